// Round 1
// baseline (88.835 us; speedup 1.0000x reference)
//
#include <hip/hip_runtime.h>

// out[i][j][o] = sum_h X[i+1][h] * X[j+1][h] * W[o][h] + b[o]
// (diff/W2 term cancels under symmetrization; only W[:, :768] is live)
//
// X: (512, 768) fp32, W: (2, 1536) fp32, b: (2,) fp32
// out: (510, 510, 2) fp32

constexpr int H     = 768;
constexpr int M     = 510;   // output rows/cols
constexpr int TILE  = 32;    // output tile per block
constexpr int CH    = 32;    // K chunk
constexpr int CH4   = CH / 4;        // float4s per row-chunk
constexpr int LDW4  = CH4 + 1;       // padded row stride in float4 (36 floats)

__global__ __launch_bounds__(256) void pairwise_head_kernel(
    const float* __restrict__ X, const float* __restrict__ W,
    const float* __restrict__ bias, float* __restrict__ out) {
  __shared__ float4 xi0[TILE * LDW4];  // A rows * w0
  __shared__ float4 xi1[TILE * LDW4];  // A rows * w1
  __shared__ float4 xjr[TILE * LDW4];  // B rows raw

  const int tid = threadIdx.x;
  const int tx = tid & 15;   // j micro-tile index
  const int ty = tid >> 4;   // i micro-tile index
  const int gi0 = blockIdx.y * TILE;
  const int gj0 = blockIdx.x * TILE;

  // staging assignment: one float4 of each array per thread per chunk
  const int sr = tid >> 3;   // row 0..31
  const int sc = tid & 7;    // float4 col 0..7
  int xi_row = gi0 + 1 + sr; if (xi_row > 511) xi_row = 511;  // clamp (guarded at store)
  int xj_row = gj0 + 1 + sr; if (xj_row > 511) xj_row = 511;

  float acc[2][2][2] = {};   // [di][dj][o]

  for (int ck = 0; ck < H / CH; ++ck) {
    const int h0 = ck * CH + sc * 4;
    const float4 xv = *(const float4*)(X + xi_row * H + h0);
    const float4 w0 = *(const float4*)(W + h0);
    const float4 w1 = *(const float4*)(W + 1536 + h0);
    const float4 yv = *(const float4*)(X + xj_row * H + h0);
    __syncthreads();   // protect previous iteration's LDS reads
    xi0[sr * LDW4 + sc] = make_float4(xv.x * w0.x, xv.y * w0.y, xv.z * w0.z, xv.w * w0.w);
    xi1[sr * LDW4 + sc] = make_float4(xv.x * w1.x, xv.y * w1.y, xv.z * w1.z, xv.w * w1.w);
    xjr[sr * LDW4 + sc] = yv;
    __syncthreads();

#pragma unroll
    for (int c = 0; c < CH4; ++c) {
      const float4 a00 = xi0[(2 * ty + 0) * LDW4 + c];
      const float4 a01 = xi1[(2 * ty + 0) * LDW4 + c];
      const float4 a10 = xi0[(2 * ty + 1) * LDW4 + c];
      const float4 a11 = xi1[(2 * ty + 1) * LDW4 + c];
      const float4 p   = xjr[(2 * tx + 0) * LDW4 + c];
      const float4 q   = xjr[(2 * tx + 1) * LDW4 + c];
#define PW_STEP(comp)                                         \
      acc[0][0][0] = fmaf(a00.comp, p.comp, acc[0][0][0]);    \
      acc[0][1][0] = fmaf(a00.comp, q.comp, acc[0][1][0]);    \
      acc[0][0][1] = fmaf(a01.comp, p.comp, acc[0][0][1]);    \
      acc[0][1][1] = fmaf(a01.comp, q.comp, acc[0][1][1]);    \
      acc[1][0][0] = fmaf(a10.comp, p.comp, acc[1][0][0]);    \
      acc[1][1][0] = fmaf(a10.comp, q.comp, acc[1][1][0]);    \
      acc[1][0][1] = fmaf(a11.comp, p.comp, acc[1][0][1]);    \
      acc[1][1][1] = fmaf(a11.comp, q.comp, acc[1][1][1]);
      PW_STEP(x) PW_STEP(y) PW_STEP(z) PW_STEP(w)
#undef PW_STEP
    }
  }

  const float b0 = bias[0];
  const float b1 = bias[1];
#pragma unroll
  for (int di = 0; di < 2; ++di) {
#pragma unroll
    for (int dj = 0; dj < 2; ++dj) {
      const int oi = gi0 + 2 * ty + di;
      const int oj = gj0 + 2 * tx + dj;
      if (oi < M && oj < M) {
        float2 v = make_float2(acc[di][dj][0] + b0, acc[di][dj][1] + b1);
        *(float2*)(out + ((size_t)oi * M + oj) * 2) = v;
      }
    }
  }
}

extern "C" void kernel_launch(void* const* d_in, const int* in_sizes, int n_in,
                              void* d_out, int out_size, void* d_ws, size_t ws_size,
                              hipStream_t stream) {
  const float* X    = (const float*)d_in[0];  // (1, 512, 768)
  const float* W    = (const float*)d_in[1];  // (2, 1536)
  const float* bias = (const float*)d_in[2];  // (2,)
  float* out = (float*)d_out;                 // (510, 510, 2)

  dim3 grid(16, 16);   // 16*32 = 512 >= 510 in each dim
  dim3 block(256);
  hipLaunchKernelGGL(pairwise_head_kernel, grid, block, 0, stream,
                     X, W, bias, out);
}

// Round 2
// 64.430 us; speedup vs baseline: 1.3788x; 1.3788x over previous
//
#include <hip/hip_runtime.h>

// out[i][j][o] = sum_h X[i+1][h] * X[j+1][h] * W[o][h] + b[o]
// (diff/W2 term cancels under symmetrization; only W[:, :768] is live)
//
// bf16 MFMA formulation: C_o = (X .* w_o)_bf16 @ (X_bf16)^T, fp32 accumulate.
// X: (512, 768) fp32, W: (2, 1536) fp32, b: (2,) fp32, out: (510, 510, 2) fp32

constexpr int H   = 768;
constexpr int M   = 510;
constexpr int BK  = 256;        // K per LDS stage (3 stages)
constexpr int LDP = BK + 8;     // padded LDS row stride in bf16 elems
                                // (264*2=528 B = 33*16 -> 16B-aligned frags;
                                //  132 dwords, 132%32=4 -> even 8/bank on b128)

typedef __attribute__((ext_vector_type(8))) short short8;   // 8 bf16 = 4 VGPRs
typedef __attribute__((ext_vector_type(4))) float f32x4;

__device__ inline unsigned short f2bf(float x) {            // RNE fp32->bf16
  unsigned int u = __float_as_uint(x);
  u += 0x7FFFu + ((u >> 16) & 1u);
  return (unsigned short)(u >> 16);
}

__device__ inline void cvt_store4(unsigned short* p, float4 v) {
  ushort4 u;
  u.x = f2bf(v.x); u.y = f2bf(v.y); u.z = f2bf(v.z); u.w = f2bf(v.w);
  *(ushort4*)p = u;   // ds_write_b64
}

__global__ __launch_bounds__(256) void pairwise_head_mfma(
    const float* __restrict__ X, const float* __restrict__ W,
    const float* __restrict__ bias, float* __restrict__ out) {
  __shared__ __align__(16) unsigned short sm[3 * 32 * LDP];  // 50,688 B
  unsigned short* sA0 = sm;                 // rows-i, * w0
  unsigned short* sA1 = sm + 32 * LDP;      // rows-i, * w1
  unsigned short* sB  = sm + 2 * 32 * LDP;  // rows-j, raw

  const int tid = threadIdx.x;
  const int gi0 = blockIdx.y * 32;
  const int gj0 = blockIdx.x * 32;

  // ---- staging assignment: 8 threads per row, 8 float4 each per stage ----
  const int srow  = tid >> 3;   // 0..31
  const int scol8 = tid & 7;    // 0..7
  int arow = gi0 + 1 + srow; if (arow > 511) arow = 511;  // clamped, guarded at store
  int brow = gj0 + 1 + srow; if (brow > 511) brow = 511;
  const float4* Xa = (const float4*)(X + (size_t)arow * H);
  const float4* Xb = (const float4*)(X + (size_t)brow * H);
  const float4* W0 = (const float4*)(W);
  const float4* W1 = (const float4*)(W + 1536);

  // ---- compute assignment: wave = output quadrant (mi, nj), full K ----
  const int wave = tid >> 6;
  const int lane = tid & 63;
  const int lo = lane & 15;     // frag row (A) / col (B)
  const int q  = lane >> 4;     // quad -> k-subgroup
  const int mi = wave >> 1;
  const int nj = wave & 1;
  const unsigned short* pa0 = sA0 + (mi * 16 + lo) * LDP + q * 8;
  const unsigned short* pa1 = sA1 + (mi * 16 + lo) * LDP + q * 8;
  const unsigned short* pb  = sB  + (nj * 16 + lo) * LDP + q * 8;

  f32x4 acc0 = {0.f, 0.f, 0.f, 0.f};
  f32x4 acc1 = {0.f, 0.f, 0.f, 0.f};

  for (int st = 0; st < H / BK; ++st) {
    if (st > 0) __syncthreads();            // previous stage fully consumed
    const int g4 = st * (BK / 4);           // global float4 col base
#pragma unroll
    for (int s = 0; s < 8; ++s) {
      const int c  = scol8 + 8 * s;         // float4 col within stage, 0..63
      const float4 xv  = Xa[g4 + c];
      const float4 w0v = W0[g4 + c];
      const float4 w1v = W1[g4 + c];
      const float4 yv  = Xb[g4 + c];
      cvt_store4(sA0 + srow * LDP + 4 * c,
                 make_float4(xv.x * w0v.x, xv.y * w0v.y, xv.z * w0v.z, xv.w * w0v.w));
      cvt_store4(sA1 + srow * LDP + 4 * c,
                 make_float4(xv.x * w1v.x, xv.y * w1v.y, xv.z * w1v.z, xv.w * w1v.w));
      cvt_store4(sB + srow * LDP + 4 * c, yv);
    }
    __syncthreads();

#pragma unroll
    for (int c = 0; c < BK / 32; ++c) {     // 8 chunks of K=32
      const short8 a0 = *(const short8*)(pa0 + c * 32);
      const short8 a1 = *(const short8*)(pa1 + c * 32);
      const short8 b  = *(const short8*)(pb  + c * 32);
      acc0 = __builtin_amdgcn_mfma_f32_16x16x32_bf16(a0, b, acc0, 0, 0, 0);
      acc1 = __builtin_amdgcn_mfma_f32_16x16x32_bf16(a1, b, acc1, 0, 0, 0);
    }
  }

  // ---- epilogue: D layout col=lane&15, row=quad*4+reg ----
  const float b0 = bias[0];
  const float b1 = bias[1];
  const int j = gj0 + nj * 16 + lo;
  const int i0 = gi0 + mi * 16 + q * 4;
  if (j < M) {
#pragma unroll
    for (int r = 0; r < 4; ++r) {
      const int i = i0 + r;
      if (i < M) {
        float2 v = make_float2(acc0[r] + b0, acc1[r] + b1);
        *(float2*)(out + ((size_t)i * M + j) * 2) = v;  // coalesced 128B/quad
      }
    }
  }
}

extern "C" void kernel_launch(void* const* d_in, const int* in_sizes, int n_in,
                              void* d_out, int out_size, void* d_ws, size_t ws_size,
                              hipStream_t stream) {
  const float* X    = (const float*)d_in[0];  // (1, 512, 768)
  const float* W    = (const float*)d_in[1];  // (2, 1536)
  const float* bias = (const float*)d_in[2];  // (2,)
  float* out = (float*)d_out;                 // (510, 510, 2)

  dim3 grid(16, 16);
  dim3 block(256);
  hipLaunchKernelGGL(pairwise_head_mfma, grid, block, 0, stream,
                     X, W, bias, out);
}

// Round 3
// 62.520 us; speedup vs baseline: 1.4209x; 1.0306x over previous
//
#include <hip/hip_runtime.h>
#include <hip/hip_bf16.h>

// out[i][j][o] = sum_h X[i+1][h] * X[j+1][h] * W[o][h] + b[o]
// (diff/W2 term cancels under symmetrization; only W[:, :768] is live)
//
// bf16 MFMA: C_o = (X .* w_o)_bf16 @ (X_bf16)^T, fp32 accumulate.
// 3-stage LDS staging, register-prefetch software pipeline, packed bf16 cvt.
// X: (512, 768) fp32, W: (2, 1536) fp32, b: (2,) fp32, out: (510, 510, 2) fp32

constexpr int H   = 768;
constexpr int M   = 510;
constexpr int BK  = 256;        // K per LDS stage (3 stages)
constexpr int NST = H / BK;     // 3
constexpr int LDP = BK + 8;     // padded LDS row stride in bf16 elems
                                // 528 B rows: 16B-aligned frags, 4-bank rotation

typedef __attribute__((ext_vector_type(8))) short short8;   // 8 bf16 = 4 VGPRs
typedef __attribute__((ext_vector_type(4))) float f32x4;

__device__ inline void cvt_store4(unsigned short* p, float4 v) {
  __hip_bfloat162 lo = __float22bfloat162_rn(make_float2(v.x, v.y));  // packed RNE
  __hip_bfloat162 hi = __float22bfloat162_rn(make_float2(v.z, v.w));
  uint2 u;
  u.x = *(unsigned int*)&lo;
  u.y = *(unsigned int*)&hi;
  *(uint2*)p = u;   // ds_write_b64
}

__device__ inline float4 mul4(float4 a, float4 b) {
  return make_float4(a.x * b.x, a.y * b.y, a.z * b.z, a.w * b.w);
}

__global__ __launch_bounds__(256, 1) void pairwise_head_mfma(
    const float* __restrict__ X, const float* __restrict__ W,
    const float* __restrict__ bias, float* __restrict__ out) {
  __shared__ __align__(16) unsigned short sm[3 * 32 * LDP];  // 50,688 B
  unsigned short* sA0 = sm;                 // rows-i, * w0
  unsigned short* sA1 = sm + 32 * LDP;      // rows-i, * w1
  unsigned short* sB  = sm + 2 * 32 * LDP;  // rows-j, raw

  const int tid = threadIdx.x;
  const int gi0 = blockIdx.y * 32;
  const int gj0 = blockIdx.x * 32;

  // ---- staging assignment: 8 threads per row, 8 float4 each per stage ----
  const int srow  = tid >> 3;   // 0..31
  const int scol8 = tid & 7;    // 0..7
  int arow = gi0 + 1 + srow; if (arow > 511) arow = 511;  // clamp; output masked
  int brow = gj0 + 1 + srow; if (brow > 511) brow = 511;
  const float4* Xa = (const float4*)(X + (size_t)arow * H);
  const float4* Xb = (const float4*)(X + (size_t)brow * H);
  const float4* W0 = (const float4*)(W);
  const float4* W1 = (const float4*)(W + 1536);

  // ---- compute assignment: wave = output quadrant (mi, nj), full K ----
  const int wave = tid >> 6;
  const int lane = tid & 63;
  const int lo = lane & 15;     // frag row (A) / col (B)
  const int q  = lane >> 4;     // quad -> k-subgroup
  const int mi = wave >> 1;
  const int nj = wave & 1;
  const unsigned short* pa0 = sA0 + (mi * 16 + lo) * LDP + q * 8;
  const unsigned short* pa1 = sA1 + (mi * 16 + lo) * LDP + q * 8;
  const unsigned short* pb  = sB  + (nj * 16 + lo) * LDP + q * 8;

  f32x4 acc0 = {0.f, 0.f, 0.f, 0.f};
  f32x4 acc1 = {0.f, 0.f, 0.f, 0.f};

  // ---- register prefetch pipeline: stage st+1 globals load under st MFMA ----
  float4 px[8], py[8], pw0[8], pw1[8];
#pragma unroll
  for (int s = 0; s < 8; ++s) {       // prologue: stage-0 loads
    const int c = scol8 + 8 * s;
    px[s] = Xa[c]; py[s] = Xb[c]; pw0[s] = W0[c]; pw1[s] = W1[c];
  }

#pragma unroll
  for (int st = 0; st < NST; ++st) {
    if (st > 0) __syncthreads();      // previous stage fully consumed
#pragma unroll
    for (int s = 0; s < 8; ++s) {
      const int c = scol8 + 8 * s;    // stage-local float4 col, 0..63
      cvt_store4(sA0 + srow * LDP + 4 * c, mul4(px[s], pw0[s]));
      cvt_store4(sA1 + srow * LDP + 4 * c, mul4(px[s], pw1[s]));
      cvt_store4(sB  + srow * LDP + 4 * c, py[s]);
    }
    __syncthreads();

    if (st + 1 < NST) {               // prefetch next stage; overlaps MFMA below
      const int g4 = (st + 1) * (BK / 4);
#pragma unroll
      for (int s = 0; s < 8; ++s) {
        const int c = g4 + scol8 + 8 * s;
        px[s] = Xa[c]; py[s] = Xb[c]; pw0[s] = W0[c]; pw1[s] = W1[c];
      }
    }

#pragma unroll
    for (int c = 0; c < BK / 32; ++c) {     // 8 chunks of K=32
      const short8 a0 = *(const short8*)(pa0 + c * 32);
      const short8 a1 = *(const short8*)(pa1 + c * 32);
      const short8 b  = *(const short8*)(pb  + c * 32);
      acc0 = __builtin_amdgcn_mfma_f32_16x16x32_bf16(a0, b, acc0, 0, 0, 0);
      acc1 = __builtin_amdgcn_mfma_f32_16x16x32_bf16(a1, b, acc1, 0, 0, 0);
    }
  }

  // ---- epilogue: D layout col=lane&15, row=quad*4+reg ----
  const float b0 = bias[0];
  const float b1 = bias[1];
  const int j  = gj0 + nj * 16 + lo;
  const int i0 = gi0 + mi * 16 + q * 4;
  if (j < M) {
#pragma unroll
    for (int r = 0; r < 4; ++r) {
      const int i = i0 + r;
      if (i < M) {
        float2 v = make_float2(acc0[r] + b0, acc1[r] + b1);
        *(float2*)(out + ((size_t)i * M + j) * 2) = v;  // coalesced 128B/quad
      }
    }
  }
}

extern "C" void kernel_launch(void* const* d_in, const int* in_sizes, int n_in,
                              void* d_out, int out_size, void* d_ws, size_t ws_size,
                              hipStream_t stream) {
  const float* X    = (const float*)d_in[0];  // (1, 512, 768)
  const float* W    = (const float*)d_in[1];  // (2, 1536)
  const float* bias = (const float*)d_in[2];  // (2,)
  float* out = (float*)d_out;                 // (510, 510, 2)

  dim3 grid(16, 16);
  dim3 block(256);
  hipLaunchKernelGGL(pairwise_head_mfma, grid, block, 0, stream,
                     X, W, bias, out);
}